// Round 7
// baseline (481.340 us; speedup 1.0000x reference)
//
#include <hip/hip_runtime.h>
#include <hip/hip_bf16.h>

#define NODES 100000
#define EDGES 1600000
#define NBINS ((NODES + 127) >> 7)              // 782 coarse bins, 128 nodes each
#define BINCAP 2560                             // padded bin capacity (mean 2048, sd 45)
#define SB_BLOCKS 64
#define SB_CHUNK (EDGES / SB_BLOCKS)            // 25000 edges per scatter block
#define CAST_BLOCKS 12500                       // 3.2M float4 casts / 256
#define WPREP_BLOCKS 176                        // 45056/256 weight-prep blocks

typedef __bf16 bf16x8 __attribute__((ext_vector_type(8)));
typedef float f32x4 __attribute__((ext_vector_type(4)));

__device__ __forceinline__ unsigned short f2b(float f) {
  __hip_bfloat16 h = __float2bfloat16(f);   // RNE
  return __builtin_bit_cast(unsigned short, h);
}
__device__ __forceinline__ float b_lo(unsigned u) { return __uint_as_float(u << 16); }
__device__ __forceinline__ float b_hi(unsigned u) { return __uint_as_float(u & 0xffff0000u); }

// ---------------------------------------------------------------------------
// prep_count: fused x-cast (row-major bf16) + weight transpose/cast + zero
// of the per-bin atomic counters.
// ---------------------------------------------------------------------------
__global__ __launch_bounds__(256) void prep_count(
    const float4* __restrict__ x4, ushort4* __restrict__ xh4,
    const float* __restrict__ W1, const float* __restrict__ W2,
    const float* __restrict__ W3, const float* __restrict__ W4,
    unsigned short* __restrict__ Wt1, unsigned short* __restrict__ Wt2,
    unsigned short* __restrict__ Wt3, unsigned short* __restrict__ Wt4,
    int* __restrict__ cnt) {
  const int b = blockIdx.x;
  if (b < CAST_BLOCKS) {
    int i = b * 256 + threadIdx.x;
    float4 v = x4[i];
    ushort4 o;
    o.x = f2b(v.x); o.y = f2b(v.y); o.z = f2b(v.z); o.w = f2b(v.w);
    xh4[i] = o;
    return;
  }
  if (b < CAST_BLOCKS + WPREP_BLOCKS) {
    int i = (b - CAST_BLOCKS) * 256 + threadIdx.x;
    if (i < 16384) {                       // Wt1 [128][128]
      int n = i >> 7, k = i & 127;
      Wt1[i] = f2b(W1[k * 128 + n]);
    } else if (i < 32768) {                // Wt2 [128][128]
      int j = i - 16384; int n = j >> 7, k = j & 127;
      Wt2[j] = f2b(W2[k * 128 + n]);
    } else if (i < 40960) {                // Wt3 [64][128]  (K=128,N=64)
      int j = i - 32768; int n = j >> 7, k = j & 127;
      Wt3[j] = f2b(W3[k * 64 + n]);
    } else if (i < 45056) {                // Wt4 [64][64]
      int j = i - 40960; int n = j >> 6, k = j & 63;
      Wt4[j] = f2b(W4[k * 64 + n]);
    }
    return;
  }
  for (int i = threadIdx.x; i < NBINS; i += 256) cnt[i] = 0;
}

// ---------------------------------------------------------------------------
// bin_scatter v2: 64 blocks x 25000 edges. Stage payloads in LDS bins
// (histogram -> two-level prefix scan -> LDS scatter), reserve global ranges
// with one atomicAdd per (bin,block), then dump each bin as a CONTIGUOUS run
// (~128B coalesced writes) instead of 1.6M random 4B write-allocates.
// ---------------------------------------------------------------------------
__global__ __launch_bounds__(256) void bin_scatter(const int* __restrict__ src,
                                                   const int* __restrict__ dst,
                                                   int* __restrict__ cnt,
                                                   unsigned* __restrict__ coarse) {
  __shared__ unsigned pay[SB_CHUNK];   // 100 KB payload staging
  __shared__ int h[NBINS];
  __shared__ int lofs[NBINS];
  __shared__ int gbase[NBINS];
  __shared__ int cur[NBINS];
  __shared__ int ssc[256];
  const int t = threadIdx.x;
  const int beg = blockIdx.x * SB_CHUNK;
  const int end = min(beg + SB_CHUNK, EDGES);

  for (int i = t; i < NBINS; i += 256) h[i] = 0;
  __syncthreads();
  // pass 1: histogram
  for (int e = beg + t; e < end; e += 256)
    atomicAdd(&h[dst[e] >> 7], 1);
  __syncthreads();
  // two-level exclusive scan over h -> lofs (local bin offsets)
  int own = 0;
  {
    int lim = min(t * 4 + 4, NBINS);
    for (int i = t * 4; i < lim; i++) own += h[i];
    ssc[t] = own;
  }
  __syncthreads();
  for (int off = 1; off < 256; off <<= 1) {
    int u = (t >= off) ? ssc[t - off] : 0;
    __syncthreads();
    ssc[t] += u;
    __syncthreads();
  }
  {
    int run = ssc[t] - own;
    int lim = min(t * 4 + 4, NBINS);
    for (int i = t * 4; i < lim; i++) { lofs[i] = run; run += h[i]; }
  }
  // reserve global ranges
  for (int i = t; i < NBINS; i += 256) {
    int c = h[i];
    gbase[i] = (c > 0) ? atomicAdd(&cnt[i], c) : 0;
    cur[i] = 0;
  }
  __syncthreads();
  // pass 2: scatter into LDS bins
  for (int e = beg + t; e < end; e += 256) {
    int d = dst[e];
    int b = d >> 7;
    int p = atomicAdd(&cur[b], 1);
    pay[lofs[b] + p] = (unsigned)src[e] | ((unsigned)(d & 127) << 17);
  }
  __syncthreads();
  // pass 3: per-bin coalesced dump
  const int wave = t >> 6, lane = t & 63;
  for (int i = wave; i < NBINS; i += 4) {
    int c = h[i];
    int lo = lofs[i];
    size_t gb = (size_t)i * BINCAP + gbase[i];
    for (int l = lane; l < c; l += 64) coarse[gb + l] = pay[lo + l];
  }
}

// ---------------------------------------------------------------------------
// bin_fine: one block per bin (128 nodes), LDS counting sort. Emits per-node
// (start,end) int2 pairs (absolute indices into the padded bucket array).
// ---------------------------------------------------------------------------
__global__ __launch_bounds__(256) void bin_fine(const unsigned* __restrict__ coarse,
                                                const int* __restrict__ cnt,
                                                int2* __restrict__ rowpairs,
                                                int* __restrict__ bucket) {
  __shared__ unsigned ent[BINCAP];
  __shared__ unsigned obuf[BINCAP];
  __shared__ int deg[128];
  __shared__ int pre[128];
  const int b = blockIdx.x;
  const int t = threadIdx.x;
  const int s0 = b * BINCAP;
  const int nE = cnt[b];
  const int binBase = b << 7;

  if (t < 128) deg[t] = 0;
  __syncthreads();
  for (int i = t; i < nE; i += 256) {
    unsigned e = coarse[s0 + i];
    ent[i] = e;
    atomicAdd(&deg[e >> 17], 1);
  }
  __syncthreads();
  int v = 0;
  if (t < 128) {
    v = deg[t];
    pre[t] = v;
  }
  __syncthreads();
  for (int off = 1; off < 128; off <<= 1) {
    int u = (t >= off && t < 128) ? pre[t - off] : 0;
    __syncthreads();
    if (t < 128) pre[t] += u;
    __syncthreads();
  }
  if (t < 128) {
    int inc = pre[t];
    int ex = inc - v;
    if (binBase + t < NODES) rowpairs[binBase + t] = make_int2(s0 + ex, s0 + inc);
    deg[t] = ex;  // reuse as cursor
  }
  __syncthreads();
  for (int i = t; i < nE; i += 256) {
    unsigned e = ent[i];
    int pos = atomicAdd(&deg[e >> 17], 1);
    obuf[pos] = e & 0x1FFFFu;
  }
  __syncthreads();
  for (int i = t; i < nE; i += 256) bucket[s0 + i] = (int)obuf[i];
}

// accumulate 8 bf16 features of one gathered row (packed in uint4 r), mask m
#define ACC8(r, m)                                                            \
  a[0] = fmaf(b_lo(r.x), m, a[0]); a[1] = fmaf(b_hi(r.x), m, a[1]);           \
  a[2] = fmaf(b_lo(r.y), m, a[2]); a[3] = fmaf(b_hi(r.y), m, a[3]);           \
  a[4] = fmaf(b_lo(r.z), m, a[4]); a[5] = fmaf(b_hi(r.z), m, a[5]);           \
  a[6] = fmaf(b_lo(r.w), m, a[6]); a[7] = fmaf(b_hi(r.w), m, a[7]);

// ---------------------------------------------------------------------------
// gin_layer v2: fused gather + 2-layer MLP, NO weight staging, NO barriers.
//   - Weights are read as B-fragments straight from global (32-64KB, touched
//     by every block -> permanently L1/L2-hot). LDS = S-tile only (17.4KB)
//     -> 8 blocks/CU (was 3 at 52KB): gather phase regains full TLP.
//   - The S tile is WAVE-PRIVATE (gather rows, GEMM-A rows, t1-writeback
//     rows and epilogue rows are all wave*16+0..15), so no __syncthreads is
//     needed anywhere: each wave runs gather->GEMM1->GEMM2 independently;
//     compiler lgkmcnt ordering covers within-wave ds_write->ds_read.
// K must be 128 (16 uint4 per activation row).
// ---------------------------------------------------------------------------
template <int K, int N1, int N2, bool OUT_F32>
__global__ __launch_bounds__(256, 6) void gin_layer(
    const uint4* __restrict__ xq, const int2* __restrict__ rowpairs,
    const int* __restrict__ bucket,
    const unsigned short* __restrict__ Wa, const float* __restrict__ ba,
    const unsigned short* __restrict__ Wb, const float* __restrict__ bb,
    void* __restrict__ Cout, int M) {
  constexpr int LDA = K + 8;           // S row stride (shorts)
  constexpr int NT1 = N1 / 16, KB1 = K / 32;
  constexpr int NT2 = N2 / 16, KB2 = N1 / 32;
  __shared__ unsigned short S[64 * LDA];

  const int tid = threadIdx.x;
  const int wave = tid >> 6;
  const int lane = tid & 63;
  const int g = lane >> 4;
  const int fl = lane & 15;
  const int rowBase = blockIdx.x * 64;

  // ---- phase A: gather wave's 16 rows into S (4 nodes per pass, 16 lanes each)
  for (int p = 0; p < 4; p++) {
    const int rloc = wave * 16 + p * 4 + g;
    const int n = rowBase + rloc;
    float a[8] = {0.f, 0.f, 0.f, 0.f, 0.f, 0.f, 0.f, 0.f};
    if (n < M) {
      uint4 v = xq[(size_t)n * 16 + fl];   // self row counted once
      a[0] = b_lo(v.x); a[1] = b_hi(v.x);
      a[2] = b_lo(v.y); a[3] = b_hi(v.y);
      a[4] = b_lo(v.z); a[5] = b_hi(v.z);
      a[6] = b_lo(v.w); a[7] = b_hi(v.w);
      const int2 se = rowpairs[n];
      const int beg = se.x, end = se.y;
      for (int j = beg; j < end; j += 8) {
        int i1 = min(j + 1, end - 1), i2 = min(j + 2, end - 1),
            i3 = min(j + 3, end - 1), i4 = min(j + 4, end - 1),
            i5 = min(j + 5, end - 1), i6 = min(j + 6, end - 1),
            i7 = min(j + 7, end - 1);
        int s0 = bucket[j],  s1 = bucket[i1], s2 = bucket[i2], s3 = bucket[i3];
        int s4 = bucket[i4], s5 = bucket[i5], s6 = bucket[i6], s7 = bucket[i7];
        uint4 r0 = xq[(size_t)s0 * 16 + fl];
        uint4 r1 = xq[(size_t)s1 * 16 + fl];
        uint4 r2 = xq[(size_t)s2 * 16 + fl];
        uint4 r3 = xq[(size_t)s3 * 16 + fl];
        uint4 r4 = xq[(size_t)s4 * 16 + fl];
        uint4 r5 = xq[(size_t)s5 * 16 + fl];
        uint4 r6 = xq[(size_t)s6 * 16 + fl];
        uint4 r7 = xq[(size_t)s7 * 16 + fl];
        float m1 = (j + 1 < end) ? 1.f : 0.f;
        float m2 = (j + 2 < end) ? 1.f : 0.f;
        float m3 = (j + 3 < end) ? 1.f : 0.f;
        float m4 = (j + 4 < end) ? 1.f : 0.f;
        float m5 = (j + 5 < end) ? 1.f : 0.f;
        float m6 = (j + 6 < end) ? 1.f : 0.f;
        float m7 = (j + 7 < end) ? 1.f : 0.f;
        ACC8(r0, 1.f) ACC8(r1, m1) ACC8(r2, m2) ACC8(r3, m3)
        ACC8(r4, m4) ACC8(r5, m5) ACC8(r6, m6) ACC8(r7, m7)
      }
    }
    uint4 o;  // a[]==0 for n>=M -> zero-filled pad rows
    o.x = ((unsigned)f2b(a[1]) << 16) | f2b(a[0]);
    o.y = ((unsigned)f2b(a[3]) << 16) | f2b(a[2]);
    o.z = ((unsigned)f2b(a[5]) << 16) | f2b(a[4]);
    o.w = ((unsigned)f2b(a[7]) << 16) | f2b(a[6]);
    *(uint4*)&S[rloc * LDA + fl * 8] = o;
  }

  const int arow = wave * 16 + fl;

  // ---- GEMM1: t1 = relu(S @ Wa^T + ba), B-fragments from global (L1-hot) ----
  f32x4 acc[NT1];
#pragma unroll
  for (int c = 0; c < NT1; c++) acc[c] = (f32x4){0.f, 0.f, 0.f, 0.f};
#pragma unroll
  for (int kb = 0; kb < KB1; kb++) {
    bf16x8 av = *(const bf16x8*)&S[arow * LDA + kb * 32 + g * 8];
#pragma unroll
    for (int c = 0; c < NT1; c++) {
      bf16x8 bv = *(const bf16x8*)&Wa[(size_t)(c * 16 + fl) * K + kb * 32 + g * 8];
      acc[c] = __builtin_amdgcn_mfma_f32_16x16x32_bf16(av, bv, acc[c], 0, 0, 0);
    }
  }

  // writeback t1 into wave-private rows of S
#pragma unroll
  for (int c = 0; c < NT1; c++) {
    int col = c * 16 + fl;
    float bv = ba[col];
#pragma unroll
    for (int reg = 0; reg < 4; reg++) {
      int rloc = wave * 16 + g * 4 + reg;
      S[rloc * LDA + col] = f2b(fmaxf(acc[c][reg] + bv, 0.f));
    }
  }

  // ---- GEMM2: out = relu(t1 @ Wb^T + bb), B-fragments from global ----
  f32x4 acc2[NT2];
#pragma unroll
  for (int c = 0; c < NT2; c++) acc2[c] = (f32x4){0.f, 0.f, 0.f, 0.f};
#pragma unroll
  for (int kb = 0; kb < KB2; kb++) {
    bf16x8 av = *(const bf16x8*)&S[arow * LDA + kb * 32 + g * 8];
#pragma unroll
    for (int c = 0; c < NT2; c++) {
      bf16x8 bv = *(const bf16x8*)&Wb[(size_t)(c * 16 + fl) * N1 + kb * 32 + g * 8];
      acc2[c] = __builtin_amdgcn_mfma_f32_16x16x32_bf16(av, bv, acc2[c], 0, 0, 0);
    }
  }

#pragma unroll
  for (int c = 0; c < NT2; c++) {
    int col = c * 16 + fl;
    float bv = bb[col];
#pragma unroll
    for (int reg = 0; reg < 4; reg++) {
      int row = rowBase + wave * 16 + g * 4 + reg;
      if (row < M) {
        float v = fmaxf(acc2[c][reg] + bv, 0.f);
        if (OUT_F32)
          ((float*)Cout)[(size_t)row * N2 + col] = v;
        else
          ((unsigned short*)Cout)[(size_t)row * N2 + col] = f2b(v);
      }
    }
  }
}

// ---------------------------------------------------------------------------
// launch
// ---------------------------------------------------------------------------
extern "C" void kernel_launch(void* const* d_in, const int* in_sizes, int n_in,
                              void* d_out, int out_size, void* d_ws, size_t ws_size,
                              hipStream_t stream) {
  const float* x = (const float*)d_in[0];
  const int* ei = (const int*)d_in[1];
  const int* src = ei;               // edge_index[0]
  const int* dst = ei + EDGES;       // edge_index[1]
  const float* W1 = (const float*)d_in[2];
  const float* b1 = (const float*)d_in[3];
  const float* W2 = (const float*)d_in[4];
  const float* b2 = (const float*)d_in[5];
  const float* W3 = (const float*)d_in[6];
  const float* b3 = (const float*)d_in[7];
  const float* W4 = (const float*)d_in[8];
  const float* b4 = (const float*)d_in[9];
  float* out = (float*)d_out;

  // ---- workspace layout (16B-aligned blocks) ----
  char* ws = (char*)d_ws;
  unsigned short* xh = (unsigned short*)ws;                       // 100000*128 bf16
  unsigned short* hB = xh + (size_t)NODES * 128;                  // layer1 output
  unsigned short* Wt1 = hB + (size_t)NODES * 128;                 // 128*128
  unsigned short* Wt2 = Wt1 + 128 * 128;                          // 128*128
  unsigned short* Wt3 = Wt2 + 128 * 128;                          // 64*128
  unsigned short* Wt4 = Wt3 + 64 * 128;                           // 64*64
  int2* rowpairs = (int2*)(Wt4 + 64 * 64);                        // NODES int2
  int* cnt = (int*)(rowpairs + NODES);                            // NBINS (pad 784)
  unsigned* coarse = (unsigned*)(cnt + 784);                      // NBINS*BINCAP
  int* bucket = (int*)(coarse + (size_t)NBINS * BINCAP);          // NBINS*BINCAP

  const int gblocks = (NODES + 63) / 64;

  // ---- prep + CSR build ----
  prep_count<<<CAST_BLOCKS + WPREP_BLOCKS + 1, 256, 0, stream>>>(
      (const float4*)x, (ushort4*)xh, W1, W2, W3, W4, Wt1, Wt2, Wt3, Wt4, cnt);
  bin_scatter<<<SB_BLOCKS, 256, 0, stream>>>(src, dst, cnt, coarse);
  bin_fine<<<NBINS, 256, 0, stream>>>(coarse, cnt, rowpairs, bucket);

  // ---- fused layers ----
  gin_layer<128, 128, 128, false><<<gblocks, 256, 0, stream>>>(
      (const uint4*)xh, rowpairs, bucket, Wt1, b1, Wt2, b2, hB, NODES);
  gin_layer<128, 64, 64, true><<<gblocks, 256, 0, stream>>>(
      (const uint4*)hB, rowpairs, bucket, Wt3, b3, Wt4, b4, out, NODES);
}

// Round 8
// 369.708 us; speedup vs baseline: 1.3019x; 1.3019x over previous
//
#include <hip/hip_runtime.h>
#include <hip/hip_bf16.h>

#define NODES 100000
#define EDGES 1600000
#define NBINS ((NODES + 127) >> 7)              // 782 coarse bins, 128 nodes each
#define BINCAP 2560                             // padded bin capacity (mean 2048, sd 45)
#define PB_BLOCKS 256
#define PB_CHUNK ((EDGES + PB_BLOCKS - 1) / PB_BLOCKS)  // 6250 edges per block
#define CAST_BLOCKS 12500                       // 3.2M float4 casts / 256
#define WPREP_BLOCKS 176                        // 45056/256 weight-prep blocks

typedef __bf16 bf16x8 __attribute__((ext_vector_type(8)));
typedef float f32x4 __attribute__((ext_vector_type(4)));

__device__ __forceinline__ unsigned short f2b(float f) {
  __hip_bfloat16 h = __float2bfloat16(f);   // RNE
  return __builtin_bit_cast(unsigned short, h);
}
__device__ __forceinline__ float b_lo(unsigned u) { return __uint_as_float(u << 16); }
__device__ __forceinline__ float b_hi(unsigned u) { return __uint_as_float(u & 0xffff0000u); }

// ---------------------------------------------------------------------------
// prep_count: fused x-cast (row-major bf16) + weight transpose/cast + zero
// of the per-bin atomic counters.
// ---------------------------------------------------------------------------
__global__ __launch_bounds__(256) void prep_count(
    const float4* __restrict__ x4, ushort4* __restrict__ xh4,
    const float* __restrict__ W1, const float* __restrict__ W2,
    const float* __restrict__ W3, const float* __restrict__ W4,
    unsigned short* __restrict__ Wt1, unsigned short* __restrict__ Wt2,
    unsigned short* __restrict__ Wt3, unsigned short* __restrict__ Wt4,
    int* __restrict__ cnt) {
  const int b = blockIdx.x;
  if (b < CAST_BLOCKS) {
    int i = b * 256 + threadIdx.x;
    float4 v = x4[i];
    ushort4 o;
    o.x = f2b(v.x); o.y = f2b(v.y); o.z = f2b(v.z); o.w = f2b(v.w);
    xh4[i] = o;
    return;
  }
  if (b < CAST_BLOCKS + WPREP_BLOCKS) {
    int i = (b - CAST_BLOCKS) * 256 + threadIdx.x;
    if (i < 16384) {                       // Wt1 [128][128]
      int n = i >> 7, k = i & 127;
      Wt1[i] = f2b(W1[k * 128 + n]);
    } else if (i < 32768) {                // Wt2 [128][128]
      int j = i - 16384; int n = j >> 7, k = j & 127;
      Wt2[j] = f2b(W2[k * 128 + n]);
    } else if (i < 40960) {                // Wt3 [64][128]  (K=128,N=64)
      int j = i - 32768; int n = j >> 7, k = j & 127;
      Wt3[j] = f2b(W3[k * 64 + n]);
    } else if (i < 45056) {                // Wt4 [64][64]
      int j = i - 40960; int n = j >> 6, k = j & 63;
      Wt4[j] = f2b(W4[k * 64 + n]);
    }
    return;
  }
  for (int i = threadIdx.x; i < NBINS; i += 256) cnt[i] = 0;
}

// ---------------------------------------------------------------------------
// bin_scatter (R5/R6-proven): per block, count bin occupancy in LDS, reserve
// a range per touched bin via ONE global atomicAdd, scatter into padded
// coarse array. 6.3KB LDS -> full occupancy. (R7's 113KB LDS staging version
// collapsed occupancy to 1 block/CU on 64 CUs: 150us. Reverted.)
// ---------------------------------------------------------------------------
__global__ __launch_bounds__(256) void bin_scatter(const int* __restrict__ src,
                                                   const int* __restrict__ dst,
                                                   int* __restrict__ cnt,
                                                   unsigned* __restrict__ coarse) {
  __shared__ int base[NBINS];
  __shared__ int h[NBINS];
  const int beg = blockIdx.x * PB_CHUNK;
  const int end = min(beg + PB_CHUNK, EDGES);
  for (int i = threadIdx.x; i < NBINS; i += 256) h[i] = 0;
  __syncthreads();
  for (int e = beg + threadIdx.x; e < end; e += 256)
    atomicAdd(&h[dst[e] >> 7], 1);
  __syncthreads();
  for (int i = threadIdx.x; i < NBINS; i += 256) {
    int c = h[i];
    if (c > 0) base[i] = atomicAdd(&cnt[i], c);
    h[i] = 0;  // reuse as local cursor
  }
  __syncthreads();
  for (int e = beg + threadIdx.x; e < end; e += 256) {
    int d = dst[e];
    int b = d >> 7;
    int pos = base[b] + atomicAdd(&h[b], 1);
    coarse[(size_t)b * BINCAP + pos] = (unsigned)src[e] | ((unsigned)(d & 127) << 17);
  }
}

// ---------------------------------------------------------------------------
// bin_fine: one block per bin (128 nodes), LDS counting sort. Emits per-node
// (start,end) int2 pairs (absolute indices into the padded bucket array).
// ---------------------------------------------------------------------------
__global__ __launch_bounds__(256) void bin_fine(const unsigned* __restrict__ coarse,
                                                const int* __restrict__ cnt,
                                                int2* __restrict__ rowpairs,
                                                int* __restrict__ bucket) {
  __shared__ unsigned ent[BINCAP];
  __shared__ unsigned obuf[BINCAP];
  __shared__ int deg[128];
  __shared__ int pre[128];
  const int b = blockIdx.x;
  const int t = threadIdx.x;
  const int s0 = b * BINCAP;
  const int nE = cnt[b];
  const int binBase = b << 7;

  if (t < 128) deg[t] = 0;
  __syncthreads();
  for (int i = t; i < nE; i += 256) {
    unsigned e = coarse[s0 + i];
    ent[i] = e;
    atomicAdd(&deg[e >> 17], 1);
  }
  __syncthreads();
  int v = 0;
  if (t < 128) {
    v = deg[t];
    pre[t] = v;
  }
  __syncthreads();
  for (int off = 1; off < 128; off <<= 1) {
    int u = (t >= off && t < 128) ? pre[t - off] : 0;
    __syncthreads();
    if (t < 128) pre[t] += u;
    __syncthreads();
  }
  if (t < 128) {
    int inc = pre[t];
    int ex = inc - v;
    if (binBase + t < NODES) rowpairs[binBase + t] = make_int2(s0 + ex, s0 + inc);
    deg[t] = ex;  // reuse as cursor
  }
  __syncthreads();
  for (int i = t; i < nE; i += 256) {
    unsigned e = ent[i];
    int pos = atomicAdd(&deg[e >> 17], 1);
    obuf[pos] = e & 0x1FFFFu;
  }
  __syncthreads();
  for (int i = t; i < nE; i += 256) bucket[s0 + i] = (int)obuf[i];
}

// accumulate 8 bf16 features of one gathered row (packed in uint4 r), mask m
#define ACC8(r, m)                                                            \
  a[0] = fmaf(b_lo(r.x), m, a[0]); a[1] = fmaf(b_hi(r.x), m, a[1]);           \
  a[2] = fmaf(b_lo(r.y), m, a[2]); a[3] = fmaf(b_hi(r.y), m, a[3]);           \
  a[4] = fmaf(b_lo(r.z), m, a[4]); a[5] = fmaf(b_hi(r.z), m, a[5]);           \
  a[6] = fmaf(b_lo(r.w), m, a[6]); a[7] = fmaf(b_hi(r.w), m, a[7]);

// ---------------------------------------------------------------------------
// gin_layer v2: fused gather + 2-layer MLP, NO weight staging, NO barriers.
//   - Weights read as B-fragments straight from global (L1/L2-hot: every
//     block touches the same 32-64KB). LDS = S-tile only (17.4KB).
//   - S tile is WAVE-PRIVATE -> no __syncthreads anywhere; each wave runs
//     gather->GEMM1->GEMM2 independently.
// K must be 128 (16 uint4 per activation row).
// ---------------------------------------------------------------------------
template <int K, int N1, int N2, bool OUT_F32>
__global__ __launch_bounds__(256, 6) void gin_layer(
    const uint4* __restrict__ xq, const int2* __restrict__ rowpairs,
    const int* __restrict__ bucket,
    const unsigned short* __restrict__ Wa, const float* __restrict__ ba,
    const unsigned short* __restrict__ Wb, const float* __restrict__ bb,
    void* __restrict__ Cout, int M) {
  constexpr int LDA = K + 8;           // S row stride (shorts)
  constexpr int NT1 = N1 / 16, KB1 = K / 32;
  constexpr int NT2 = N2 / 16, KB2 = N1 / 32;
  __shared__ unsigned short S[64 * LDA];

  const int tid = threadIdx.x;
  const int wave = tid >> 6;
  const int lane = tid & 63;
  const int g = lane >> 4;
  const int fl = lane & 15;
  const int rowBase = blockIdx.x * 64;

  // ---- phase A: gather wave's 16 rows into S (4 nodes per pass, 16 lanes each)
  for (int p = 0; p < 4; p++) {
    const int rloc = wave * 16 + p * 4 + g;
    const int n = rowBase + rloc;
    float a[8] = {0.f, 0.f, 0.f, 0.f, 0.f, 0.f, 0.f, 0.f};
    if (n < M) {
      uint4 v = xq[(size_t)n * 16 + fl];   // self row counted once
      a[0] = b_lo(v.x); a[1] = b_hi(v.x);
      a[2] = b_lo(v.y); a[3] = b_hi(v.y);
      a[4] = b_lo(v.z); a[5] = b_hi(v.z);
      a[6] = b_lo(v.w); a[7] = b_hi(v.w);
      const int2 se = rowpairs[n];
      const int beg = se.x, end = se.y;
      for (int j = beg; j < end; j += 8) {
        int i1 = min(j + 1, end - 1), i2 = min(j + 2, end - 1),
            i3 = min(j + 3, end - 1), i4 = min(j + 4, end - 1),
            i5 = min(j + 5, end - 1), i6 = min(j + 6, end - 1),
            i7 = min(j + 7, end - 1);
        int s0 = bucket[j],  s1 = bucket[i1], s2 = bucket[i2], s3 = bucket[i3];
        int s4 = bucket[i4], s5 = bucket[i5], s6 = bucket[i6], s7 = bucket[i7];
        uint4 r0 = xq[(size_t)s0 * 16 + fl];
        uint4 r1 = xq[(size_t)s1 * 16 + fl];
        uint4 r2 = xq[(size_t)s2 * 16 + fl];
        uint4 r3 = xq[(size_t)s3 * 16 + fl];
        uint4 r4 = xq[(size_t)s4 * 16 + fl];
        uint4 r5 = xq[(size_t)s5 * 16 + fl];
        uint4 r6 = xq[(size_t)s6 * 16 + fl];
        uint4 r7 = xq[(size_t)s7 * 16 + fl];
        float m1 = (j + 1 < end) ? 1.f : 0.f;
        float m2 = (j + 2 < end) ? 1.f : 0.f;
        float m3 = (j + 3 < end) ? 1.f : 0.f;
        float m4 = (j + 4 < end) ? 1.f : 0.f;
        float m5 = (j + 5 < end) ? 1.f : 0.f;
        float m6 = (j + 6 < end) ? 1.f : 0.f;
        float m7 = (j + 7 < end) ? 1.f : 0.f;
        ACC8(r0, 1.f) ACC8(r1, m1) ACC8(r2, m2) ACC8(r3, m3)
        ACC8(r4, m4) ACC8(r5, m5) ACC8(r6, m6) ACC8(r7, m7)
      }
    }
    uint4 o;  // a[]==0 for n>=M -> zero-filled pad rows
    o.x = ((unsigned)f2b(a[1]) << 16) | f2b(a[0]);
    o.y = ((unsigned)f2b(a[3]) << 16) | f2b(a[2]);
    o.z = ((unsigned)f2b(a[5]) << 16) | f2b(a[4]);
    o.w = ((unsigned)f2b(a[7]) << 16) | f2b(a[6]);
    *(uint4*)&S[rloc * LDA + fl * 8] = o;
  }

  const int arow = wave * 16 + fl;

  // ---- GEMM1: t1 = relu(S @ Wa^T + ba), B-fragments from global (L1-hot) ----
  f32x4 acc[NT1];
#pragma unroll
  for (int c = 0; c < NT1; c++) acc[c] = (f32x4){0.f, 0.f, 0.f, 0.f};
#pragma unroll
  for (int kb = 0; kb < KB1; kb++) {
    bf16x8 av = *(const bf16x8*)&S[arow * LDA + kb * 32 + g * 8];
#pragma unroll
    for (int c = 0; c < NT1; c++) {
      bf16x8 bv = *(const bf16x8*)&Wa[(size_t)(c * 16 + fl) * K + kb * 32 + g * 8];
      acc[c] = __builtin_amdgcn_mfma_f32_16x16x32_bf16(av, bv, acc[c], 0, 0, 0);
    }
  }

  // writeback t1 into wave-private rows of S
#pragma unroll
  for (int c = 0; c < NT1; c++) {
    int col = c * 16 + fl;
    float bv = ba[col];
#pragma unroll
    for (int reg = 0; reg < 4; reg++) {
      int rloc = wave * 16 + g * 4 + reg;
      S[rloc * LDA + col] = f2b(fmaxf(acc[c][reg] + bv, 0.f));
    }
  }

  // ---- GEMM2: out = relu(t1 @ Wb^T + bb), B-fragments from global ----
  f32x4 acc2[NT2];
#pragma unroll
  for (int c = 0; c < NT2; c++) acc2[c] = (f32x4){0.f, 0.f, 0.f, 0.f};
#pragma unroll
  for (int kb = 0; kb < KB2; kb++) {
    bf16x8 av = *(const bf16x8*)&S[arow * LDA + kb * 32 + g * 8];
#pragma unroll
    for (int c = 0; c < NT2; c++) {
      bf16x8 bv = *(const bf16x8*)&Wb[(size_t)(c * 16 + fl) * N1 + kb * 32 + g * 8];
      acc2[c] = __builtin_amdgcn_mfma_f32_16x16x32_bf16(av, bv, acc2[c], 0, 0, 0);
    }
  }

#pragma unroll
  for (int c = 0; c < NT2; c++) {
    int col = c * 16 + fl;
    float bv = bb[col];
#pragma unroll
    for (int reg = 0; reg < 4; reg++) {
      int row = rowBase + wave * 16 + g * 4 + reg;
      if (row < M) {
        float v = fmaxf(acc2[c][reg] + bv, 0.f);
        if (OUT_F32)
          ((float*)Cout)[(size_t)row * N2 + col] = v;
        else
          ((unsigned short*)Cout)[(size_t)row * N2 + col] = f2b(v);
      }
    }
  }
}

// ---------------------------------------------------------------------------
// launch
// ---------------------------------------------------------------------------
extern "C" void kernel_launch(void* const* d_in, const int* in_sizes, int n_in,
                              void* d_out, int out_size, void* d_ws, size_t ws_size,
                              hipStream_t stream) {
  const float* x = (const float*)d_in[0];
  const int* ei = (const int*)d_in[1];
  const int* src = ei;               // edge_index[0]
  const int* dst = ei + EDGES;       // edge_index[1]
  const float* W1 = (const float*)d_in[2];
  const float* b1 = (const float*)d_in[3];
  const float* W2 = (const float*)d_in[4];
  const float* b2 = (const float*)d_in[5];
  const float* W3 = (const float*)d_in[6];
  const float* b3 = (const float*)d_in[7];
  const float* W4 = (const float*)d_in[8];
  const float* b4 = (const float*)d_in[9];
  float* out = (float*)d_out;

  // ---- workspace layout (16B-aligned blocks) ----
  char* ws = (char*)d_ws;
  unsigned short* xh = (unsigned short*)ws;                       // 100000*128 bf16
  unsigned short* hB = xh + (size_t)NODES * 128;                  // layer1 output
  unsigned short* Wt1 = hB + (size_t)NODES * 128;                 // 128*128
  unsigned short* Wt2 = Wt1 + 128 * 128;                          // 128*128
  unsigned short* Wt3 = Wt2 + 128 * 128;                          // 64*128
  unsigned short* Wt4 = Wt3 + 64 * 128;                           // 64*64
  int2* rowpairs = (int2*)(Wt4 + 64 * 64);                        // NODES int2
  int* cnt = (int*)(rowpairs + NODES);                            // NBINS (pad 784)
  unsigned* coarse = (unsigned*)(cnt + 784);                      // NBINS*BINCAP
  int* bucket = (int*)(coarse + (size_t)NBINS * BINCAP);          // NBINS*BINCAP

  const int gblocks = (NODES + 63) / 64;

  // ---- prep + CSR build ----
  prep_count<<<CAST_BLOCKS + WPREP_BLOCKS + 1, 256, 0, stream>>>(
      (const float4*)x, (ushort4*)xh, W1, W2, W3, W4, Wt1, Wt2, Wt3, Wt4, cnt);
  bin_scatter<<<PB_BLOCKS, 256, 0, stream>>>(src, dst, cnt, coarse);
  bin_fine<<<NBINS, 256, 0, stream>>>(coarse, cnt, rowpairs, bucket);

  // ---- fused layers ----
  gin_layer<128, 128, 128, false><<<gblocks, 256, 0, stream>>>(
      (const uint4*)xh, rowpairs, bucket, Wt1, b1, Wt2, b2, hB, NODES);
  gin_layer<128, 64, 64, true><<<gblocks, 256, 0, stream>>>(
      (const uint4*)hB, rowpairs, bucket, Wt3, b3, Wt4, b4, out, NODES);
}

// Round 9
// 310.119 us; speedup vs baseline: 1.5521x; 1.1922x over previous
//
#include <hip/hip_runtime.h>
#include <hip/hip_bf16.h>

#define NODES 100000
#define EDGES 1600000
#define NBINS ((NODES + 127) >> 7)              // 782 coarse bins, 128 nodes each
#define BINCAP 2560                             // padded bin capacity (mean 2048, sd 45)
#define PB_BLOCKS 256
#define PB_CHUNK ((EDGES + PB_BLOCKS - 1) / PB_BLOCKS)  // 6250 edges per block
#define CAST_BLOCKS 12500                       // 3.2M float4 casts / 256
#define WPREP_BLOCKS 176                        // 45056/256 weight-prep blocks

typedef __bf16 bf16x8 __attribute__((ext_vector_type(8)));
typedef float f32x4 __attribute__((ext_vector_type(4)));

__device__ __forceinline__ unsigned short f2b(float f) {
  __hip_bfloat16 h = __float2bfloat16(f);   // RNE
  return __builtin_bit_cast(unsigned short, h);
}
__device__ __forceinline__ float b_lo(unsigned u) { return __uint_as_float(u << 16); }
__device__ __forceinline__ float b_hi(unsigned u) { return __uint_as_float(u & 0xffff0000u); }

// ---------------------------------------------------------------------------
// prep_count: fused x-cast (row-major bf16) + weight transpose/cast + zero
// of the per-bin atomic counters.
// ---------------------------------------------------------------------------
__global__ __launch_bounds__(256) void prep_count(
    const float4* __restrict__ x4, ushort4* __restrict__ xh4,
    const float* __restrict__ W1, const float* __restrict__ W2,
    const float* __restrict__ W3, const float* __restrict__ W4,
    unsigned short* __restrict__ Wt1, unsigned short* __restrict__ Wt2,
    unsigned short* __restrict__ Wt3, unsigned short* __restrict__ Wt4,
    int* __restrict__ cnt) {
  const int b = blockIdx.x;
  if (b < CAST_BLOCKS) {
    int i = b * 256 + threadIdx.x;
    float4 v = x4[i];
    ushort4 o;
    o.x = f2b(v.x); o.y = f2b(v.y); o.z = f2b(v.z); o.w = f2b(v.w);
    xh4[i] = o;
    return;
  }
  if (b < CAST_BLOCKS + WPREP_BLOCKS) {
    int i = (b - CAST_BLOCKS) * 256 + threadIdx.x;
    if (i < 16384) {                       // Wt1 [128][128]
      int n = i >> 7, k = i & 127;
      Wt1[i] = f2b(W1[k * 128 + n]);
    } else if (i < 32768) {                // Wt2 [128][128]
      int j = i - 16384; int n = j >> 7, k = j & 127;
      Wt2[j] = f2b(W2[k * 128 + n]);
    } else if (i < 40960) {                // Wt3 [64][128]  (K=128,N=64)
      int j = i - 32768; int n = j >> 7, k = j & 127;
      Wt3[j] = f2b(W3[k * 64 + n]);
    } else if (i < 45056) {                // Wt4 [64][64]
      int j = i - 40960; int n = j >> 6, k = j & 63;
      Wt4[j] = f2b(W4[k * 64 + n]);
    }
    return;
  }
  for (int i = threadIdx.x; i < NBINS; i += 256) cnt[i] = 0;
}

// ---------------------------------------------------------------------------
// bin_scatter (R5-proven): per block, count bin occupancy in LDS, reserve a
// range per touched bin via ONE global atomicAdd, scatter into padded array.
// ---------------------------------------------------------------------------
__global__ __launch_bounds__(256) void bin_scatter(const int* __restrict__ src,
                                                   const int* __restrict__ dst,
                                                   int* __restrict__ cnt,
                                                   unsigned* __restrict__ coarse) {
  __shared__ int base[NBINS];
  __shared__ int h[NBINS];
  const int beg = blockIdx.x * PB_CHUNK;
  const int end = min(beg + PB_CHUNK, EDGES);
  for (int i = threadIdx.x; i < NBINS; i += 256) h[i] = 0;
  __syncthreads();
  for (int e = beg + threadIdx.x; e < end; e += 256)
    atomicAdd(&h[dst[e] >> 7], 1);
  __syncthreads();
  for (int i = threadIdx.x; i < NBINS; i += 256) {
    int c = h[i];
    if (c > 0) base[i] = atomicAdd(&cnt[i], c);
    h[i] = 0;  // reuse as local cursor
  }
  __syncthreads();
  for (int e = beg + threadIdx.x; e < end; e += 256) {
    int d = dst[e];
    int b = d >> 7;
    int pos = base[b] + atomicAdd(&h[b], 1);
    coarse[(size_t)b * BINCAP + pos] = (unsigned)src[e] | ((unsigned)(d & 127) << 17);
  }
}

// ---------------------------------------------------------------------------
// bin_fine: one block per bin (128 nodes), LDS counting sort. Emits per-node
// (start,end) int2 pairs (absolute indices into the padded bucket array).
// ---------------------------------------------------------------------------
__global__ __launch_bounds__(256) void bin_fine(const unsigned* __restrict__ coarse,
                                                const int* __restrict__ cnt,
                                                int2* __restrict__ rowpairs,
                                                int* __restrict__ bucket) {
  __shared__ unsigned ent[BINCAP];
  __shared__ unsigned obuf[BINCAP];
  __shared__ int deg[128];
  __shared__ int pre[128];
  const int b = blockIdx.x;
  const int t = threadIdx.x;
  const int s0 = b * BINCAP;
  const int nE = cnt[b];
  const int binBase = b << 7;

  if (t < 128) deg[t] = 0;
  __syncthreads();
  for (int i = t; i < nE; i += 256) {
    unsigned e = coarse[s0 + i];
    ent[i] = e;
    atomicAdd(&deg[e >> 17], 1);
  }
  __syncthreads();
  int v = 0;
  if (t < 128) {
    v = deg[t];
    pre[t] = v;
  }
  __syncthreads();
  for (int off = 1; off < 128; off <<= 1) {
    int u = (t >= off && t < 128) ? pre[t - off] : 0;
    __syncthreads();
    if (t < 128) pre[t] += u;
    __syncthreads();
  }
  if (t < 128) {
    int inc = pre[t];
    int ex = inc - v;
    if (binBase + t < NODES) rowpairs[binBase + t] = make_int2(s0 + ex, s0 + inc);
    deg[t] = ex;  // reuse as cursor
  }
  __syncthreads();
  for (int i = t; i < nE; i += 256) {
    unsigned e = ent[i];
    int pos = atomicAdd(&deg[e >> 17], 1);
    obuf[pos] = e & 0x1FFFFu;
  }
  __syncthreads();
  for (int i = t; i < nE; i += 256) bucket[s0 + i] = (int)obuf[i];
}

// accumulate 8 bf16 features of one gathered row (packed in uint4 r), mask m
#define ACC8(r, m)                                                            \
  a[0] = fmaf(b_lo(r.x), m, a[0]); a[1] = fmaf(b_hi(r.x), m, a[1]);           \
  a[2] = fmaf(b_lo(r.y), m, a[2]); a[3] = fmaf(b_hi(r.y), m, a[3]);           \
  a[4] = fmaf(b_lo(r.z), m, a[4]); a[5] = fmaf(b_hi(r.z), m, a[5]);           \
  a[6] = fmaf(b_lo(r.w), m, a[6]); a[7] = fmaf(b_hi(r.w), m, a[7]);

// ---------------------------------------------------------------------------
// gin_layer v3: fused gather + 2-layer MLP with HALF-N weight staging.
//   R8 proved global-B MFMA is latency-poisoned (VGPR-starved pipelining:
//   128us, VALU 20%). R6 proved LDS-B works but 52KB LDS killed occupancy
//   (2 blocks/CU, 89us). v3 stages weights 64 output-rows at a time:
//   Wl = 64x136x2 = 17.4KB; total LDS 34,816B -> 4 blocks/CU (16 waves).
//   S stays wave-private (no barrier for gather); Wa half 0 is staged BEFORE
//   the gather so its latency hides under gather compute. Barriers only
//   around weight (re)staging: 7 for layer1 (N1=N2=128), 3 for layer2.
// K must be 128; N1,N2 in {64,128}.
// ---------------------------------------------------------------------------
template <int K, int N1, int N2, bool OUT_F32>
__global__ __launch_bounds__(256, 4) void gin_layer(
    const uint4* __restrict__ xq, const int2* __restrict__ rowpairs,
    const int* __restrict__ bucket,
    const unsigned short* __restrict__ Wa, const float* __restrict__ ba,
    const unsigned short* __restrict__ Wb, const float* __restrict__ bb,
    void* __restrict__ Cout, int M) {
  constexpr int LDA = K + 8;           // S row stride (shorts)
  constexpr int LWA = K + 8;           // Wa row stride in Wl
  constexpr int LWB = N1 + 8;          // Wb row stride in Wl (N1 <= K)
  constexpr int NT1 = N1 / 16, KB1 = K / 32;
  constexpr int NT2 = N2 / 16, KB2 = N1 / 32;
  constexpr int NH1 = N1 / 64;         // GEMM1 staging phases
  constexpr int NH2 = N2 / 64;         // GEMM2 staging phases
  __shared__ unsigned short S[64 * LDA];     // 17408 B
  __shared__ unsigned short Wl[64 * LWA];    // 17408 B  (LWB <= LWA)

  const int tid = threadIdx.x;
  const int wave = tid >> 6;
  const int lane = tid & 63;
  const int g = lane >> 4;
  const int fl = lane & 15;
  const int rowBase = blockIdx.x * 64;

  // stage Wa half 0 early: latency hides under the gather phase
  for (int i = tid; i < 64 * (K / 8); i += 256) {
    int n = i / (K / 8), c2 = i % (K / 8);
    *(uint4*)&Wl[n * LWA + c2 * 8] = *(const uint4*)&Wa[(size_t)n * K + c2 * 8];
  }

  // ---- phase A: gather wave's 16 rows into S (4 nodes per pass) ----
  for (int p = 0; p < 4; p++) {
    const int rloc = wave * 16 + p * 4 + g;
    const int n = rowBase + rloc;
    float a[8] = {0.f, 0.f, 0.f, 0.f, 0.f, 0.f, 0.f, 0.f};
    if (n < M) {
      uint4 v = xq[(size_t)n * 16 + fl];   // self row counted once
      a[0] = b_lo(v.x); a[1] = b_hi(v.x);
      a[2] = b_lo(v.y); a[3] = b_hi(v.y);
      a[4] = b_lo(v.z); a[5] = b_hi(v.z);
      a[6] = b_lo(v.w); a[7] = b_hi(v.w);
      const int2 se = rowpairs[n];
      const int beg = se.x, end = se.y;
      for (int j = beg; j < end; j += 8) {
        int i1 = min(j + 1, end - 1), i2 = min(j + 2, end - 1),
            i3 = min(j + 3, end - 1), i4 = min(j + 4, end - 1),
            i5 = min(j + 5, end - 1), i6 = min(j + 6, end - 1),
            i7 = min(j + 7, end - 1);
        int s0 = bucket[j],  s1 = bucket[i1], s2 = bucket[i2], s3 = bucket[i3];
        int s4 = bucket[i4], s5 = bucket[i5], s6 = bucket[i6], s7 = bucket[i7];
        uint4 r0 = xq[(size_t)s0 * 16 + fl];
        uint4 r1 = xq[(size_t)s1 * 16 + fl];
        uint4 r2 = xq[(size_t)s2 * 16 + fl];
        uint4 r3 = xq[(size_t)s3 * 16 + fl];
        uint4 r4 = xq[(size_t)s4 * 16 + fl];
        uint4 r5 = xq[(size_t)s5 * 16 + fl];
        uint4 r6 = xq[(size_t)s6 * 16 + fl];
        uint4 r7 = xq[(size_t)s7 * 16 + fl];
        float m1 = (j + 1 < end) ? 1.f : 0.f;
        float m2 = (j + 2 < end) ? 1.f : 0.f;
        float m3 = (j + 3 < end) ? 1.f : 0.f;
        float m4 = (j + 4 < end) ? 1.f : 0.f;
        float m5 = (j + 5 < end) ? 1.f : 0.f;
        float m6 = (j + 6 < end) ? 1.f : 0.f;
        float m7 = (j + 7 < end) ? 1.f : 0.f;
        ACC8(r0, 1.f) ACC8(r1, m1) ACC8(r2, m2) ACC8(r3, m3)
        ACC8(r4, m4) ACC8(r5, m5) ACC8(r6, m6) ACC8(r7, m7)
      }
    }
    uint4 o;  // a[]==0 for n>=M -> zero-filled pad rows
    o.x = ((unsigned)f2b(a[1]) << 16) | f2b(a[0]);
    o.y = ((unsigned)f2b(a[3]) << 16) | f2b(a[2]);
    o.z = ((unsigned)f2b(a[5]) << 16) | f2b(a[4]);
    o.w = ((unsigned)f2b(a[7]) << 16) | f2b(a[6]);
    *(uint4*)&S[rloc * LDA + fl * 8] = o;
  }
  __syncthreads();   // Wa half 0 staged; S rows are wave-private (no dep)

  const int arow = wave * 16 + fl;

  // ---- GEMM1: t1 = relu(S @ Wa^T + ba), Wa staged 64 rows per phase ----
  f32x4 acc[NT1];
#pragma unroll
  for (int c = 0; c < NT1; c++) acc[c] = (f32x4){0.f, 0.f, 0.f, 0.f};
#pragma unroll
  for (int h = 0; h < NH1; h++) {
    if (h > 0) {
      __syncthreads();   // all waves done reading previous half
      for (int i = tid; i < 64 * (K / 8); i += 256) {
        int n = i / (K / 8), c2 = i % (K / 8);
        *(uint4*)&Wl[n * LWA + c2 * 8] =
            *(const uint4*)&Wa[(size_t)(h * 64 + n) * K + c2 * 8];
      }
      __syncthreads();
    }
#pragma unroll
    for (int kb = 0; kb < KB1; kb++) {
      bf16x8 av = *(const bf16x8*)&S[arow * LDA + kb * 32 + g * 8];
#pragma unroll
      for (int cl = 0; cl < 4; cl++) {
        bf16x8 bv = *(const bf16x8*)&Wl[(cl * 16 + fl) * LWA + kb * 32 + g * 8];
        acc[h * 4 + cl] =
            __builtin_amdgcn_mfma_f32_16x16x32_bf16(av, bv, acc[h * 4 + cl], 0, 0, 0);
      }
    }
  }

  // writeback t1 into wave-private rows of S
#pragma unroll
  for (int c = 0; c < NT1; c++) {
    int col = c * 16 + fl;
    float bv = ba[col];
#pragma unroll
    for (int reg = 0; reg < 4; reg++) {
      int rloc = wave * 16 + g * 4 + reg;
      S[rloc * LDA + col] = f2b(fmaxf(acc[c][reg] + bv, 0.f));
    }
  }

  // ---- GEMM2: out = relu(t1 @ Wb^T + bb), Wb staged 64 rows per phase ----
  f32x4 acc2[NT2];
#pragma unroll
  for (int c = 0; c < NT2; c++) acc2[c] = (f32x4){0.f, 0.f, 0.f, 0.f};
#pragma unroll
  for (int h = 0; h < NH2; h++) {
    __syncthreads();   // all waves done reading Wl (Wa tail / prev Wb half)
    for (int i = tid; i < 64 * (N1 / 8); i += 256) {
      int n = i / (N1 / 8), c2 = i % (N1 / 8);
      *(uint4*)&Wl[n * LWB + c2 * 8] =
          *(const uint4*)&Wb[(size_t)(h * 64 + n) * N1 + c2 * 8];
    }
    __syncthreads();
#pragma unroll
    for (int kb = 0; kb < KB2; kb++) {
      bf16x8 av = *(const bf16x8*)&S[arow * LDA + kb * 32 + g * 8];
#pragma unroll
      for (int cl = 0; cl < 4; cl++) {
        bf16x8 bv = *(const bf16x8*)&Wl[(cl * 16 + fl) * LWB + kb * 32 + g * 8];
        acc2[h * 4 + cl] =
            __builtin_amdgcn_mfma_f32_16x16x32_bf16(av, bv, acc2[h * 4 + cl], 0, 0, 0);
      }
    }
  }

#pragma unroll
  for (int c = 0; c < NT2; c++) {
    int col = c * 16 + fl;
    float bv = bb[col];
#pragma unroll
    for (int reg = 0; reg < 4; reg++) {
      int row = rowBase + wave * 16 + g * 4 + reg;
      if (row < M) {
        float v = fmaxf(acc2[c][reg] + bv, 0.f);
        if (OUT_F32)
          ((float*)Cout)[(size_t)row * N2 + col] = v;
        else
          ((unsigned short*)Cout)[(size_t)row * N2 + col] = f2b(v);
      }
    }
  }
}

// ---------------------------------------------------------------------------
// launch
// ---------------------------------------------------------------------------
extern "C" void kernel_launch(void* const* d_in, const int* in_sizes, int n_in,
                              void* d_out, int out_size, void* d_ws, size_t ws_size,
                              hipStream_t stream) {
  const float* x = (const float*)d_in[0];
  const int* ei = (const int*)d_in[1];
  const int* src = ei;               // edge_index[0]
  const int* dst = ei + EDGES;       // edge_index[1]
  const float* W1 = (const float*)d_in[2];
  const float* b1 = (const float*)d_in[3];
  const float* W2 = (const float*)d_in[4];
  const float* b2 = (const float*)d_in[5];
  const float* W3 = (const float*)d_in[6];
  const float* b3 = (const float*)d_in[7];
  const float* W4 = (const float*)d_in[8];
  const float* b4 = (const float*)d_in[9];
  float* out = (float*)d_out;

  // ---- workspace layout (16B-aligned blocks) ----
  char* ws = (char*)d_ws;
  unsigned short* xh = (unsigned short*)ws;                       // 100000*128 bf16
  unsigned short* hB = xh + (size_t)NODES * 128;                  // layer1 output
  unsigned short* Wt1 = hB + (size_t)NODES * 128;                 // 128*128
  unsigned short* Wt2 = Wt1 + 128 * 128;                          // 128*128
  unsigned short* Wt3 = Wt2 + 128 * 128;                          // 64*128
  unsigned short* Wt4 = Wt3 + 64 * 128;                           // 64*64
  int2* rowpairs = (int2*)(Wt4 + 64 * 64);                        // NODES int2
  int* cnt = (int*)(rowpairs + NODES);                            // NBINS (pad 784)
  unsigned* coarse = (unsigned*)(cnt + 784);                      // NBINS*BINCAP
  int* bucket = (int*)(coarse + (size_t)NBINS * BINCAP);          // NBINS*BINCAP

  const int gblocks = (NODES + 63) / 64;

  // ---- prep + CSR build ----
  prep_count<<<CAST_BLOCKS + WPREP_BLOCKS + 1, 256, 0, stream>>>(
      (const float4*)x, (ushort4*)xh, W1, W2, W3, W4, Wt1, Wt2, Wt3, Wt4, cnt);
  bin_scatter<<<PB_BLOCKS, 256, 0, stream>>>(src, dst, cnt, coarse);
  bin_fine<<<NBINS, 256, 0, stream>>>(coarse, cnt, rowpairs, bucket);

  // ---- fused layers ----
  gin_layer<128, 128, 128, false><<<gblocks, 256, 0, stream>>>(
      (const uint4*)xh, rowpairs, bucket, Wt1, b1, Wt2, b2, hB, NODES);
  gin_layer<128, 64, 64, true><<<gblocks, 256, 0, stream>>>(
      (const uint4*)hB, rowpairs, bucket, Wt3, b3, Wt4, b4, out, NODES);
}